// Round 2
// baseline (809.219 us; speedup 1.0000x reference)
//
#include <hip/hip_runtime.h>
#include <math.h>

#define cB 4
#define cT 2048
#define cD 1024
#define cE 6
#define cP 36
#define cDA 512
#define SCALE 0.03125f
#define LN_EPS 1e-5f
#define THRESH 0.3f
#define NW 128          // online-softmax partials per (e,b)
#define ROWS 16         // T / NW rows per wave

// workspace offsets (in floats)
#define OFF_QK      0          // E*D            = 6144
#define OFF_XBAR    6144       // E*B*D          = 24576
#define OFF_FORM    30720      // E*B*D          = 24576
#define OFF_C       55296      // P*B*2DA        = 147456
#define OFF_H       202752     // P*B*DA         = 73728
#define OFF_HS      276480     // P*B*D          = 147456
#define OFF_INS     423936     // P*B*D          = 147456
#define OFF_STR     571392     // P*B            = 144
#define OFF_MASK    571536     // P              = 36
#define OFF_CNT     571572     // [flag, inv_count]
#define OFF_NORMED  571576     // B*D            = 4096
#define OFF_ADD     575672     // B*D            = 4096
#define OFF_APART   579768     // 24*NW*1024     = 3145728
#define OFF_MS      3725496    // 24*NW*2        = 6144

__device__ __forceinline__ float gelu_f(float x){
  return 0.5f * x * (1.f + erff(x * 0.70710678118654752440f));
}

// init accumulation buffers with their biases (ws re-poisoned each call)
__global__ void k_init(float* __restrict__ ws,
                       const float* __restrict__ bv, const float* __restrict__ ba,
                       const float* __restrict__ bb, const float* __restrict__ b1,
                       const float* __restrict__ bs1, const float* __restrict__ bs2,
                       const float* __restrict__ outb){
  int i = blockIdx.x * 256 + threadIdx.x;
  if (i < 24576){ int f = i & 1023; int e = i >> 12; ws[OFF_FORM + i] = bv[e*cD + f]; return; }
  i -= 24576;
  if (i < 147456){ int j = i & 1023; int p = i >> 12;
    ws[OFF_C + i] = (j < cDA) ? ba[p*cDA + j] : bb[p*cDA + j - cDA]; return; }
  i -= 147456;
  if (i < 73728){ int j = i & 511; int p = i >> 11; ws[OFF_H + i] = b1[p*cDA + j]; return; }
  i -= 73728;
  if (i < 147456){ int j = i & 1023; int p = i >> 12; ws[OFF_HS + i] = bs1[p*cD + j]; return; }
  i -= 147456;
  if (i < 147456){ int j = i & 1023; int p = i >> 12; ws[OFF_INS + i] = bs2[p*cD + j]; return; }
  i -= 147456;
  if (i < 4096){ ws[OFF_ADD + i] = outb[i & 1023]; return; }
}

// qk_eff[e,d] = sum_f Wk[e,d,f] * q[e,f]   (one wave per (e,d) row)
__global__ void k_qk(const float* __restrict__ Wk, const float* __restrict__ q,
                     float* __restrict__ qk){
  int wid = (blockIdx.x * 256 + threadIdx.x) >> 6;
  int lane = threadIdx.x & 63;
  if (wid >= cE * cD) return;
  int e = wid >> 10;
  const float4* wrow = (const float4*)(Wk + (size_t)wid * cD);
  const float4* qrow = (const float4*)(q + e * cD);
  float acc = 0.f;
  #pragma unroll
  for (int it = 0; it < 4; ++it){
    float4 w4 = wrow[it*64 + lane];
    float4 q4 = qrow[it*64 + lane];
    acc += w4.x*q4.x + w4.y*q4.y + w4.z*q4.z + w4.w*q4.w;
  }
  for (int off = 32; off; off >>= 1) acc += __shfl_down(acc, off);
  if (lane == 0) qk[wid] = acc;
}

// fused logits + online softmax + weighted accumulate, one eo pass.
// one wave per (e,b,seg): processes ROWS rows, keeps running (m,s) and a
// 1024-dim accumulator A distributed 16 floats/lane. Writes partials.
__global__ void k_fused(const float* __restrict__ eo, const float* __restrict__ ew,
                        const float* __restrict__ qk, float* __restrict__ Apart,
                        float* __restrict__ ms){
  int gw = (blockIdx.x * 256 + threadIdx.x) >> 6;   // 0..3071
  int lane = threadIdx.x & 63;
  int eb = gw >> 7;            // / NW
  int seg = gw & (NW - 1);
  int e = eb >> 2, b = eb & 3;
  const float4* q4 = (const float4*)(qk + e * cD);
  float4 qv0 = q4[lane], qv1 = q4[64 + lane], qv2 = q4[128 + lane], qv3 = q4[192 + lane];
  float4 A0 = {0,0,0,0}, A1 = {0,0,0,0}, A2 = {0,0,0,0}, A3 = {0,0,0,0};
  float m = -INFINITY, s = 0.f;
  size_t rowbase = (size_t)eb * cT + seg * ROWS;
  const float* ewb = ew + ((size_t)b * cT + seg * ROWS) * cE + e;
  for (int r = 0; r < ROWS; ++r){
    const float4* row = (const float4*)(eo + (rowbase + r) * cD);
    float4 x0 = row[lane], x1 = row[64 + lane], x2 = row[128 + lane], x3 = row[192 + lane];
    float dot = x0.x*qv0.x + x0.y*qv0.y + x0.z*qv0.z + x0.w*qv0.w
              + x1.x*qv1.x + x1.y*qv1.y + x1.z*qv1.z + x1.w*qv1.w
              + x2.x*qv2.x + x2.y*qv2.y + x2.z*qv2.z + x2.w*qv2.w
              + x3.x*qv3.x + x3.y*qv3.y + x3.z*qv3.z + x3.w*qv3.w;
    #pragma unroll
    for (int off = 1; off < 64; off <<= 1) dot += __shfl_xor(dot, off);
    float ewv = ewb[r * cE];
    float l = dot * ewv * SCALE;
    float mnew = fmaxf(m, l);
    float corr = __expf(m - mnew);       // 0 on first row (m = -inf)
    float f = __expf(l - mnew);
    s = s * corr + f;
    float g = f * ewv;                   // xbar accumulates attn * ew * eo
    A0.x = A0.x*corr + g*x0.x; A0.y = A0.y*corr + g*x0.y; A0.z = A0.z*corr + g*x0.z; A0.w = A0.w*corr + g*x0.w;
    A1.x = A1.x*corr + g*x1.x; A1.y = A1.y*corr + g*x1.y; A1.z = A1.z*corr + g*x1.z; A1.w = A1.w*corr + g*x1.w;
    A2.x = A2.x*corr + g*x2.x; A2.y = A2.y*corr + g*x2.y; A2.z = A2.z*corr + g*x2.z; A2.w = A2.w*corr + g*x2.w;
    A3.x = A3.x*corr + g*x3.x; A3.y = A3.y*corr + g*x3.y; A3.z = A3.z*corr + g*x3.z; A3.w = A3.w*corr + g*x3.w;
    m = mnew;
  }
  float4* Ap = (float4*)(Apart + (size_t)gw * cD);
  Ap[lane] = A0; Ap[64 + lane] = A1; Ap[128 + lane] = A2; Ap[192 + lane] = A3;
  if (lane == 0){ ms[gw*2] = m; ms[gw*2 + 1] = s; }
}

// merge NW partials per (e,b) -> xbar[e,b,:]
__global__ void k_merge(const float* __restrict__ Apart, const float* __restrict__ ms,
                        float* __restrict__ xbar){
  int bid = blockIdx.x;            // eb*16 + dch
  int dch = bid & 15; int eb = bid >> 4;
  int tid = threadIdx.x;
  __shared__ float wgt[NW];
  __shared__ float red[NW];
  if (tid < NW) red[tid] = ms[(eb*NW + tid)*2];
  __syncthreads();
  for (int s = 64; s; s >>= 1){ if (tid < s) red[tid] = fmaxf(red[tid], red[tid+s]); __syncthreads(); }
  float M = red[0]; __syncthreads();
  if (tid < NW){
    float mi = ms[(eb*NW + tid)*2], si = ms[(eb*NW + tid)*2 + 1];
    float f = __expf(mi - M);
    wgt[tid] = f;
    red[tid] = si * f;
  }
  __syncthreads();
  for (int s = 64; s; s >>= 1){ if (tid < s) red[tid] += red[tid+s]; __syncthreads(); }
  float invS = 1.f / red[0];
  __syncthreads();
  int d = dch*64 + (tid & 63);
  int ig = tid >> 6;
  float acc = 0.f;
  for (int i = ig; i < NW; i += 4)
    acc += Apart[((size_t)(eb*NW + i))*cD + d] * wgt[i];
  __shared__ float r2[4][64];
  r2[ig][tid & 63] = acc;
  __syncthreads();
  if (ig == 0)
    xbar[eb*cD + d] = (r2[0][tid&63] + r2[1][tid&63] + r2[2][tid&63] + r2[3][tid&63]) * invS;
}

// formulas[e,b,f] += sum_{d in chunk} xbar[e,b,d] * Wv[e,d,f]
__global__ void k_formulas(const float* __restrict__ Wv, const float* __restrict__ xbar,
                           float* __restrict__ form){
  int bid = blockIdx.x;
  int dch = bid & 7; bid >>= 3;
  int fch = bid & 3; bid >>= 2;
  int e = bid;
  int tid = threadIdx.x;
  __shared__ float4 xl[128];
  if (tid < 128){
    float4 v;
    v.x = xbar[(e*cB+0)*cD + dch*128 + tid];
    v.y = xbar[(e*cB+1)*cD + dch*128 + tid];
    v.z = xbar[(e*cB+2)*cD + dch*128 + tid];
    v.w = xbar[(e*cB+3)*cD + dch*128 + tid];
    xl[tid] = v;
  }
  __syncthreads();
  float a0=0,a1=0,a2=0,a3=0;
  const float* wbase = Wv + (size_t)e*cD*cD + (size_t)(dch*128)*cD + fch*256 + tid;
  #pragma unroll 8
  for (int dd = 0; dd < 128; ++dd){
    float w = wbase[(size_t)dd * cD];
    float4 x = xl[dd];
    a0 += x.x*w; a1 += x.y*w; a2 += x.z*w; a3 += x.w*w;
  }
  int o = fch*256 + tid;
  atomicAdd(&form[(e*cB+0)*cD + o], a0);
  atomicAdd(&form[(e*cB+1)*cD + o], a1);
  atomicAdd(&form[(e*cB+2)*cD + o], a2);
  atomicAdd(&form[(e*cB+3)*cD + o], a3);
}

// vectorized 4-row GEMV: out[p,b,colOff+c] += sum_{d chunk} act(in[p,b,d]) * W[p,d,c]
// block: 256 cols (64 lanes x float4) x 128-deep Din chunk, 4 d-phases reduced in LDS.
// gatherMode: 0 = in is (P,B,Din); 1 = formulas[p/6]; 2 = formulas[p%6]
__global__ void k_gemv(const float* __restrict__ in, const float* __restrict__ W,
                       float* __restrict__ out, const float* __restrict__ form,
                       int Din, int Dout, int colOff, int outStride,
                       int gatherMode, int actGelu){
  int nD = Din >> 7;
  int nC = Dout >> 8;
  int bid = blockIdx.x;
  int dch = bid % nD; bid /= nD;
  int cch = bid % nC; bid /= nC;
  int p = bid;
  int tid = threadIdx.x;
  int c4 = tid & 63;
  int dr = tid >> 6;
  int d0 = dch << 7;
  __shared__ float4 xl[128];
  const float* inbase;
  if (gatherMode){
    int e = (gatherMode == 1) ? (p / cE) : (p % cE);
    inbase = form + (size_t)e * cB * cD;
  } else {
    inbase = in + (size_t)p * cB * Din;
  }
  if (tid < 128){
    float4 v;
    v.x = inbase[0*Din + d0 + tid];
    v.y = inbase[1*Din + d0 + tid];
    v.z = inbase[2*Din + d0 + tid];
    v.w = inbase[3*Din + d0 + tid];
    if (actGelu){ v.x = gelu_f(v.x); v.y = gelu_f(v.y); v.z = gelu_f(v.z); v.w = gelu_f(v.w); }
    xl[tid] = v;
  }
  __syncthreads();
  float4 a0 = {0,0,0,0}, a1 = {0,0,0,0}, a2 = {0,0,0,0}, a3 = {0,0,0,0};
  const float4* wbase = (const float4*)(W + (size_t)p*Din*Dout + (size_t)d0*Dout + (cch<<8)) + c4;
  int wstride = Dout >> 2;
  for (int dd = dr; dd < 128; dd += 4){
    float4 w4 = wbase[(size_t)dd * wstride];
    float4 x = xl[dd];
    a0.x += x.x*w4.x; a0.y += x.x*w4.y; a0.z += x.x*w4.z; a0.w += x.x*w4.w;
    a1.x += x.y*w4.x; a1.y += x.y*w4.y; a1.z += x.y*w4.z; a1.w += x.y*w4.w;
    a2.x += x.z*w4.x; a2.y += x.z*w4.y; a2.z += x.z*w4.z; a2.w += x.z*w4.w;
    a3.x += x.w*w4.x; a3.y += x.w*w4.y; a3.z += x.w*w4.z; a3.w += x.w*w4.w;
  }
  __shared__ float4 red[4][64][4];   // [dr][c4][b]
  red[dr][c4][0] = a0; red[dr][c4][1] = a1; red[dr][c4][2] = a2; red[dr][c4][3] = a3;
  __syncthreads();
  // thread (dr,c4) now owns batch b = dr for its 4 cols
  float4 r;
  float4 t0 = red[0][c4][dr], t1 = red[1][c4][dr], t2 = red[2][c4][dr], t3 = red[3][c4][dr];
  r.x = t0.x + t1.x + t2.x + t3.x;
  r.y = t0.y + t1.y + t2.y + t3.y;
  r.z = t0.z + t1.z + t2.z + t3.z;
  r.w = t0.w + t1.w + t2.w + t3.w;
  float* op = out + (size_t)p*cB*outStride + (size_t)dr*outStride + colOff + (cch<<8) + c4*4;
  atomicAdd(op+0, r.x); atomicAdd(op+1, r.y); atomicAdd(op+2, r.z); atomicAdd(op+3, r.w);
}

// strength[p,b] = sigmoid(dot(gelu(pre_h[p,b,:]), W2[p,:]) + b2[p])
__global__ void k_strength(const float* __restrict__ pre_h, const float* __restrict__ W2,
                           const float* __restrict__ b2, float* __restrict__ str){
  int p = blockIdx.x;
  int b = threadIdx.x >> 6;
  int lane = threadIdx.x & 63;
  const float* h = pre_h + (size_t)(p*cB + b)*cDA;
  const float* w = W2 + (size_t)p*cDA;
  float acc = 0.f;
  #pragma unroll
  for (int it = 0; it < 8; ++it){
    int j = it*64 + lane;
    acc += gelu_f(h[j]) * w[j];
  }
  for (int off = 32; off; off >>= 1) acc += __shfl_down(acc, off);
  if (lane == 0) str[p*cB + b] = 1.f / (1.f + expf(-(acc + b2[p])));
}

// avg strength per pair, mask, active count; writes outputs 1 & 2
__global__ void k_combine(const float* __restrict__ str, float* __restrict__ ws,
                          float* __restrict__ out_tail){
  int tid = threadIdx.x;
  __shared__ float mk[64];
  float msk = 0.f;
  if (tid < cP){
    float avg = 0.25f * (str[tid*4] + str[tid*4+1] + str[tid*4+2] + str[tid*4+3]);
    out_tail[tid] = avg;
    msk = (avg > THRESH) ? 1.f : 0.f;
    ws[OFF_MASK + tid] = msk;
  }
  mk[tid] = msk;
  __syncthreads();
  if (tid == 0){
    float cnt = 0.f;
    for (int i = 0; i < cP; ++i) cnt += mk[i];
    out_tail[cP] = cnt;
    ws[OFF_CNT]     = (cnt > 0.f) ? 1.f : 0.f;
    ws[OFF_CNT + 1] = 1.f / fmaxf(cnt, 1.f);
  }
}

// total[b,:] = sum_p mask*strength*pair_gate*inv_cnt * insight_pre[p,b,:]; then LayerNorm
__global__ void k_totln(const float* __restrict__ ins, const float* __restrict__ str,
                        const float* __restrict__ mask, const float* __restrict__ pg,
                        const float* __restrict__ cnt2, const float* __restrict__ gamma,
                        const float* __restrict__ beta, float* __restrict__ normed){
  int b = blockIdx.x;
  int tid = threadIdx.x;
  __shared__ float sc[cP];
  __shared__ float red[256];
  if (tid < cP) sc[tid] = mask[tid] * str[tid*4 + b] * pg[tid] * cnt2[1];
  __syncthreads();
  float tot[4];
  #pragma unroll
  for (int k = 0; k < 4; ++k){
    int d = tid + k*256;
    float s = 0.f;
    for (int p = 0; p < cP; ++p) s += sc[p] * ins[(size_t)(p*cB + b)*cD + d];
    tot[k] = s;
  }
  float lsum = tot[0] + tot[1] + tot[2] + tot[3];
  red[tid] = lsum; __syncthreads();
  for (int s = 128; s; s >>= 1){ if (tid < s) red[tid] += red[tid+s]; __syncthreads(); }
  float mu = red[0] * (1.f / cD); __syncthreads();
  float q = 0.f;
  #pragma unroll
  for (int k = 0; k < 4; ++k){ float dxy = tot[k] - mu; q += dxy*dxy; }
  red[tid] = q; __syncthreads();
  for (int s = 128; s; s >>= 1){ if (tid < s) red[tid] += red[tid+s]; __syncthreads(); }
  float rs = rsqrtf(red[0] * (1.f / cD) + LN_EPS);
  #pragma unroll
  for (int k = 0; k < 4; ++k){
    int d = tid + k*256;
    normed[b*cD + d] = (tot[k] - mu) * rs * gamma[d] + beta[d];
  }
}

// add_pre[b,f] += sum_{d chunk} normed[b,d] * out_W[d,f]
__global__ void k_proj(const float* __restrict__ normed, const float* __restrict__ W,
                       float* __restrict__ addp){
  int bid = blockIdx.x;
  int dch = bid & 7; int fch = bid >> 3;
  int tid = threadIdx.x;
  __shared__ float4 nl[128];
  if (tid < 128){
    float4 v;
    v.x = normed[0*cD + dch*128 + tid];
    v.y = normed[1*cD + dch*128 + tid];
    v.z = normed[2*cD + dch*128 + tid];
    v.w = normed[3*cD + dch*128 + tid];
    nl[tid] = v;
  }
  __syncthreads();
  float a0=0,a1=0,a2=0,a3=0;
  const float* wbase = W + (size_t)(dch*128)*cD + fch*256 + tid;
  #pragma unroll 8
  for (int dd = 0; dd < 128; ++dd){
    float w = wbase[(size_t)dd * cD];
    float4 x = nl[dd];
    a0 += x.x*w; a1 += x.y*w; a2 += x.z*w; a3 += x.w*w;
  }
  int o = fch*256 + tid;
  atomicAdd(&addp[0*cD + o], a0);
  atomicAdd(&addp[1*cD + o], a1);
  atomicAdd(&addp[2*cD + o], a2);
  atomicAdd(&addp[3*cD + o], a3);
}

// out[b,t,:] = bridge[b,t,:] + flag * analogy_gate * add_pre[b,:]
__global__ void k_final(const float* __restrict__ bridge, const float* __restrict__ addp,
                        const float* __restrict__ cnt2, const float* __restrict__ gate,
                        float* __restrict__ out){
  float g = gate[0] * cnt2[0];
  const float4* b4 = (const float4*)bridge;
  const float4* a4 = (const float4*)addp;
  float4* o4 = (float4*)out;
  int total4 = cB*cT*cD/4;
  for (int i = blockIdx.x*256 + threadIdx.x; i < total4; i += gridDim.x*256){
    float4 bb = b4[i];
    int b = i >> 19;
    float4 aa = a4[b*256 + (i & 255)];
    bb.x += g*aa.x; bb.y += g*aa.y; bb.z += g*aa.z; bb.w += g*aa.w;
    o4[i] = bb;
  }
}

extern "C" void kernel_launch(void* const* d_in, const int* in_sizes, int n_in,
                              void* d_out, int out_size, void* d_ws, size_t ws_size,
                              hipStream_t stream) {
  const float* bridge = (const float*)d_in[0];
  const float* eo     = (const float*)d_in[1];
  const float* ew     = (const float*)d_in[2];
  const float* q      = (const float*)d_in[3];
  const float* Wk     = (const float*)d_in[4];
  /* cond_bk (d_in[5]) is softmax-invariant — unused */
  const float* Wv     = (const float*)d_in[6];
  const float* bv     = (const float*)d_in[7];
  const float* Wa     = (const float*)d_in[8];
  const float* ba     = (const float*)d_in[9];
  const float* Wb     = (const float*)d_in[10];
  const float* bb     = (const float*)d_in[11];
  const float* W1     = (const float*)d_in[12];
  const float* b1     = (const float*)d_in[13];
  const float* W2     = (const float*)d_in[14];
  const float* b2     = (const float*)d_in[15];
  const float* Ws1    = (const float*)d_in[16];
  const float* bs1    = (const float*)d_in[17];
  const float* Ws2    = (const float*)d_in[18];
  const float* bs2    = (const float*)d_in[19];
  const float* pg     = (const float*)d_in[20];
  const float* gamma  = (const float*)d_in[21];
  const float* beta   = (const float*)d_in[22];
  const float* outW   = (const float*)d_in[23];
  const float* outb   = (const float*)d_in[24];
  const float* agate  = (const float*)d_in[25];
  float* out = (float*)d_out;
  float* ws  = (float*)d_ws;

  k_init<<<2128, 256, 0, stream>>>(ws, bv, ba, bb, b1, bs1, bs2, outb);
  k_qk<<<1536, 256, 0, stream>>>(Wk, q, ws + OFF_QK);
  k_fused<<<768, 256, 0, stream>>>(eo, ew, ws + OFF_QK, ws + OFF_APART, ws + OFF_MS);
  k_merge<<<384, 256, 0, stream>>>(ws + OFF_APART, ws + OFF_MS, ws + OFF_XBAR);
  k_formulas<<<192, 256, 0, stream>>>(Wv, ws + OFF_XBAR, ws + OFF_FORM);
  // pair stages: a, b -> c
  k_gemv<<<576, 256, 0, stream>>>(nullptr, Wa, ws + OFF_C, ws + OFF_FORM,
                                  1024, 512, 0, 1024, 1, 0);
  k_gemv<<<576, 256, 0, stream>>>(nullptr, Wb, ws + OFF_C, ws + OFF_FORM,
                                  1024, 512, 512, 1024, 2, 0);
  // gate path: pre_h = c @ W1 + b1
  k_gemv<<<576, 256, 0, stream>>>(ws + OFF_C, W1, ws + OFF_H, nullptr,
                                  1024, 512, 0, 512, 0, 0);
  // synthesis path: pre_hs = c @ Ws1 + bs1
  k_gemv<<<1152, 256, 0, stream>>>(ws + OFF_C, Ws1, ws + OFF_HS, nullptr,
                                   1024, 1024, 0, 1024, 0, 0);
  k_strength<<<36, 256, 0, stream>>>(ws + OFF_H, W2, b2, ws + OFF_STR);
  // insight_pre = gelu(pre_hs) @ Ws2 + bs2
  k_gemv<<<1152, 256, 0, stream>>>(ws + OFF_HS, Ws2, ws + OFF_INS, nullptr,
                                   1024, 1024, 0, 1024, 0, 1);
  k_combine<<<1, 64, 0, stream>>>(ws + OFF_STR, ws, out + (size_t)cB*cT*cD);
  k_totln<<<4, 256, 0, stream>>>(ws + OFF_INS, ws + OFF_STR, ws + OFF_MASK, pg,
                                 ws + OFF_CNT, gamma, beta, ws + OFF_NORMED);
  k_proj<<<32, 256, 0, stream>>>(ws + OFF_NORMED, outW, ws + OFF_ADD);
  k_final<<<2048, 256, 0, stream>>>(bridge, ws + OFF_ADD, ws + OFF_CNT, agate, out);
}